// Round 1
// baseline (17188.234 us; speedup 1.0000x reference)
//
#include <hip/hip_runtime.h>

#define T_STEPS 4096
#define HD 512
#define G3HD 1536
#define NCODES 4880
#define NWG 16

// ---------------------------------------------------------------------------
// GEMM1: visit[4096][512] = H^T (4096x4880) @ X_emb (4880x512)
// H is stored [code][t] so A[m][k] = H[k][m]; both tiles load coalesced along
// their contiguous dims. 64x64 tile, 256 threads, 4x4 microtile.
// ---------------------------------------------------------------------------
__global__ __launch_bounds__(256) void gemm1_kernel(const float* __restrict__ H,
                                                    const float* __restrict__ X,
                                                    float* __restrict__ C) {
  __shared__ float As[16][68];
  __shared__ float Bs[16][68];
  const int m0 = blockIdx.x * 64;
  const int n0 = blockIdx.y * 64;
  const int tid = threadIdx.x;
  const int lk = tid >> 4;          // 0..15 (k row of tile)
  const int lm = (tid & 15) << 2;   // 0..60 (col within tile)
  const int tm = (tid & 15) << 2;   // micro-tile row base
  const int tn = (tid >> 4) << 2;   // micro-tile col base
  float acc[4][4] = {};
  for (int k0 = 0; k0 < NCODES; k0 += 16) {
    float4 av = *(const float4*)(H + (size_t)(k0 + lk) * T_STEPS + m0 + lm);
    float4 bv = *(const float4*)(X + (size_t)(k0 + lk) * HD + n0 + lm);
    __syncthreads();
    *(float4*)(&As[lk][lm]) = av;
    *(float4*)(&Bs[lk][lm]) = bv;
    __syncthreads();
#pragma unroll
    for (int kk = 0; kk < 16; ++kk) {
      float4 a = *(const float4*)(&As[kk][tm]);
      float4 b = *(const float4*)(&Bs[kk][tn]);
      float ar[4] = {a.x, a.y, a.z, a.w};
      float br[4] = {b.x, b.y, b.z, b.w};
#pragma unroll
      for (int i = 0; i < 4; ++i)
#pragma unroll
        for (int j = 0; j < 4; ++j) acc[i][j] += ar[i] * br[j];
    }
  }
#pragma unroll
  for (int i = 0; i < 4; ++i) {
    float4 o = make_float4(acc[i][0], acc[i][1], acc[i][2], acc[i][3]);
    *(float4*)(C + (size_t)(m0 + tm + i) * HD + n0 + tn) = o;
  }
}

// ---------------------------------------------------------------------------
// GEMM2: gi[4096][1536] = visit (4096x512) @ W_ih^T (512x1536) + b_ih
// A and B both k-contiguous -> load float4 along k, store transposed to LDS.
// ---------------------------------------------------------------------------
__global__ __launch_bounds__(256) void gemm2_kernel(const float* __restrict__ A,
                                                    const float* __restrict__ B,
                                                    const float* __restrict__ bias,
                                                    float* __restrict__ Cout) {
  __shared__ float As[16][68];
  __shared__ float Bs[16][68];
  const int m0 = blockIdx.x * 64;
  const int n0 = blockIdx.y * 64;
  const int tid = threadIdx.x;
  const int lr = tid >> 2;          // 0..63 row of tile
  const int lkq = (tid & 3) << 2;   // 0,4,8,12
  const int tm = (tid & 15) << 2;
  const int tn = (tid >> 4) << 2;
  float acc[4][4] = {};
  for (int k0 = 0; k0 < HD; k0 += 16) {
    float4 av = *(const float4*)(A + (size_t)(m0 + lr) * HD + k0 + lkq);
    float4 bv = *(const float4*)(B + (size_t)(n0 + lr) * HD + k0 + lkq);
    __syncthreads();
    As[lkq + 0][lr] = av.x; As[lkq + 1][lr] = av.y;
    As[lkq + 2][lr] = av.z; As[lkq + 3][lr] = av.w;
    Bs[lkq + 0][lr] = bv.x; Bs[lkq + 1][lr] = bv.y;
    Bs[lkq + 2][lr] = bv.z; Bs[lkq + 3][lr] = bv.w;
    __syncthreads();
#pragma unroll
    for (int kk = 0; kk < 16; ++kk) {
      float4 a = *(const float4*)(&As[kk][tm]);
      float4 b = *(const float4*)(&Bs[kk][tn]);
      float ar[4] = {a.x, a.y, a.z, a.w};
      float br[4] = {b.x, b.y, b.z, b.w};
#pragma unroll
      for (int i = 0; i < 4; ++i)
#pragma unroll
        for (int j = 0; j < 4; ++j) acc[i][j] += ar[i] * br[j];
    }
  }
  const float b0 = bias[n0 + tn + 0];
  const float b1 = bias[n0 + tn + 1];
  const float b2 = bias[n0 + tn + 2];
  const float b3 = bias[n0 + tn + 3];
#pragma unroll
  for (int i = 0; i < 4; ++i) {
    float4 o = make_float4(acc[i][0] + b0, acc[i][1] + b1, acc[i][2] + b2, acc[i][3] + b3);
    *(float4*)(Cout + (size_t)(m0 + tm + i) * G3HD + n0 + tn) = o;
  }
}

// ---------------------------------------------------------------------------
// Persistent GRU scan. 16 WGs x 384 threads. WG g owns h slice j in
// [g*32, g*32+32) and the 96 W_hh rows {j, 512+j, 1024+j}. W_hh slice lives
// in registers: thread (rg, kc) holds w[8][16] = rows rg*8..rg*8+8,
// k in [kc*16, kc*16+16). Per step: poll flags (device-scope), load h[t-1]
// from hs (agent-scope atomic loads -> XCD-coherent), matvec in regs,
// LDS tree-reduce, gates on 32 lanes, publish slice + flag (release).
// h stored in LDS transposed (hT[(k%16)*32 + k/16]) -> matvec reads are
// bank-conflict-free (bank == kc).
// ---------------------------------------------------------------------------
__global__ __launch_bounds__(384, 1) void scan_kernel(const float* __restrict__ gi,
                                                      const float* __restrict__ W_hh,
                                                      const float* __restrict__ b_hh,
                                                      const float* __restrict__ w_att,
                                                      float* __restrict__ hs,
                                                      float* __restrict__ logitp,
                                                      unsigned int* __restrict__ flags) {
  const int g = blockIdx.x;
  const int tid = threadIdx.x;
  const int rg = tid >> 5;   // 0..11 row-group
  const int kc = tid & 31;   // 0..31 k-chunk

  float w[8][16];
#pragma unroll
  for (int r = 0; r < 8; ++r) {
    const int lr = rg * 8 + r;
    const int grow = (lr >> 5) * HD + g * 32 + (lr & 31);
    const float* wp = W_hh + (size_t)grow * HD + kc * 16;
#pragma unroll
    for (int i = 0; i < 16; i += 4) {
      float4 v = *(const float4*)(wp + i);
      w[r][i + 0] = v.x; w[r][i + 1] = v.y; w[r][i + 2] = v.z; w[r][i + 3] = v.w;
    }
  }

  __shared__ float hT[512];
  __shared__ float part[96 * 33];
  __shared__ float ghb[96];
  __shared__ float gib[96];
  __shared__ float bhh_s[96];
  __shared__ float watt_s[32];

  if (tid < 96) bhh_s[tid] = b_hh[(tid >> 5) * HD + g * 32 + (tid & 31)];
  if (tid < 32) watt_s[tid] = w_att[g * 32 + tid];

  const unsigned int* hs_u = (const unsigned int*)hs;

  for (int t = 0; t < T_STEPS; ++t) {
    // issue gi prefetch early; consumed after two barriers
    float gival = 0.f;
    if (tid < 96) gival = gi[(size_t)t * G3HD + (tid >> 5) * HD + g * 32 + (tid & 31)];

    if (t > 0 && tid < NWG) {
      while (__hip_atomic_load(&flags[tid], __ATOMIC_RELAXED, __HIP_MEMORY_SCOPE_AGENT) <
             (unsigned int)t) {}
    }
    __syncthreads();
    __builtin_amdgcn_fence(__ATOMIC_ACQUIRE, "agent");

    if (tid < 128) {
      float hv[4];
      if (t > 0) {
        const size_t base = (size_t)(t - 1) * HD + tid * 4;
#pragma unroll
        for (int i = 0; i < 4; ++i) {
          unsigned int u = __hip_atomic_load(&hs_u[base + i], __ATOMIC_RELAXED,
                                             __HIP_MEMORY_SCOPE_AGENT);
          hv[i] = __uint_as_float(u);
        }
      } else {
        hv[0] = hv[1] = hv[2] = hv[3] = 0.f;
      }
      const int k0 = tid * 4;
#pragma unroll
      for (int i = 0; i < 4; ++i) hT[((k0 + i) & 15) * 32 + ((k0 + i) >> 4)] = hv[i];
    }
    if (tid < 96) gib[tid] = gival;
    __syncthreads();

    float acc[8] = {0.f, 0.f, 0.f, 0.f, 0.f, 0.f, 0.f, 0.f};
#pragma unroll
    for (int ii = 0; ii < 16; ++ii) {
      const float hv = hT[ii * 32 + kc];
#pragma unroll
      for (int r = 0; r < 8; ++r) acc[r] += w[r][ii] * hv;
    }
#pragma unroll
    for (int r = 0; r < 8; ++r) part[(rg * 8 + r) * 33 + kc] = acc[r];
    __syncthreads();

    {
      const int row = tid >> 2;  // 0..95
      const int q = tid & 3;
      float s = 0.f;
#pragma unroll
      for (int i = 0; i < 8; ++i) s += part[row * 33 + q * 8 + i];
      s += __shfl_xor(s, 1);
      s += __shfl_xor(s, 2);
      if (q == 0) ghb[row] = s + bhh_s[row];
    }
    __syncthreads();

    if (tid < 32) {
      const int j = tid;
      const float x_r = gib[j] + ghb[j];
      const float x_z = gib[32 + j] + ghb[32 + j];
      const float ghn = ghb[64 + j];
      const float r = 1.f / (1.f + expf(-x_r));
      const float z = 1.f / (1.f + expf(-x_z));
      const float n = tanhf(gib[64 + j] + r * ghn);
      const int k = g * 32 + j;
      const float hprev = hT[(k & 15) * 32 + (k >> 4)];  // zeros at t==0
      const float hnew = (1.f - z) * n + z * hprev;
      __hip_atomic_store((unsigned int*)hs + (size_t)t * HD + k, __float_as_uint(hnew),
                         __ATOMIC_RELAXED, __HIP_MEMORY_SCOPE_AGENT);
      float lp = watt_s[j] * hnew;
      lp += __shfl_xor(lp, 1);
      lp += __shfl_xor(lp, 2);
      lp += __shfl_xor(lp, 4);
      lp += __shfl_xor(lp, 8);
      lp += __shfl_xor(lp, 16);
      if (j == 0) {
        logitp[t * NWG + g] = lp;
        __hip_atomic_store(&flags[g], (unsigned int)(t + 1), __ATOMIC_RELEASE,
                           __HIP_MEMORY_SCOPE_AGENT);
      }
    }
  }
}

// ---------------------------------------------------------------------------
// Softmax over 4096 logits (reduce 16 partials each), write alpha; zero out.
// ---------------------------------------------------------------------------
__global__ __launch_bounds__(256) void softmax_kernel(const float* __restrict__ logitp,
                                                      float* __restrict__ alpha,
                                                      float* __restrict__ out) {
  __shared__ float tmp[4];
  const int tid = threadIdx.x;
  float l[16];
  float m = -1e30f;
#pragma unroll
  for (int i = 0; i < 16; ++i) {
    const int t = i * 256 + tid;
    float s = 0.f;
#pragma unroll
    for (int gg = 0; gg < NWG; ++gg) s += logitp[t * NWG + gg];
    l[i] = s;
    m = fmaxf(m, s);
  }
#pragma unroll
  for (int o = 32; o > 0; o >>= 1) m = fmaxf(m, __shfl_xor(m, o));
  if ((tid & 63) == 0) tmp[tid >> 6] = m;
  __syncthreads();
  m = fmaxf(fmaxf(tmp[0], tmp[1]), fmaxf(tmp[2], tmp[3]));
  __syncthreads();
  float e[16];
  float s = 0.f;
#pragma unroll
  for (int i = 0; i < 16; ++i) {
    e[i] = expf(l[i] - m);
    s += e[i];
  }
#pragma unroll
  for (int o = 32; o > 0; o >>= 1) s += __shfl_xor(s, o);
  if ((tid & 63) == 0) tmp[tid >> 6] = s;
  __syncthreads();
  s = tmp[0] + tmp[1] + tmp[2] + tmp[3];
  const float inv = 1.f / s;
#pragma unroll
  for (int i = 0; i < 16; ++i) alpha[i * 256 + tid] = e[i] * inv;
  out[tid] = 0.f;
  out[256 + tid] = 0.f;
}

// ---------------------------------------------------------------------------
// out[j] = sum_t alpha[t] * hs[t][j].  128 WGs: 2 j-halves x 64 t-chunks.
// ---------------------------------------------------------------------------
__global__ __launch_bounds__(256) void wsum_kernel(const float* __restrict__ alpha,
                                                   const float* __restrict__ hs,
                                                   float* __restrict__ out) {
  const int tid = threadIdx.x;
  const int jblk = (blockIdx.x & 1) * 256;
  const int tc = blockIdx.x >> 1;
  float acc = 0.f;
  for (int tt = 0; tt < 64; ++tt) {
    const int t = tc * 64 + tt;
    acc += alpha[t] * hs[(size_t)t * HD + jblk + tid];
  }
  atomicAdd(&out[jblk + tid], acc);
}

extern "C" void kernel_launch(void* const* d_in, const int* in_sizes, int n_in,
                              void* d_out, int out_size, void* d_ws, size_t ws_size,
                              hipStream_t stream) {
  const float* H     = (const float*)d_in[0];
  // d_in[1] = TE, unused by the reference
  const float* X_emb = (const float*)d_in[2];
  const float* W_ih  = (const float*)d_in[3];
  const float* W_hh  = (const float*)d_in[4];
  const float* b_ih  = (const float*)d_in[5];
  const float* b_hh  = (const float*)d_in[6];
  const float* w_att = (const float*)d_in[7];
  float* out = (float*)d_out;

  char* ws = (char*)d_ws;
  float* visit        = (float*)(ws + 0);          //  8 MB: 4096x512
  float* gi           = (float*)(ws + 8388608);    // 25 MB: 4096x1536
  float* hs           = (float*)(ws + 33554432);   //  8 MB: 4096x512
  float* logitp       = (float*)(ws + 41943040);   // 256 KB: 4096x16
  float* alpha        = (float*)(ws + 42205184);   // 16 KB
  unsigned int* flags = (unsigned int*)(ws + 42221568);

  hipMemsetAsync(flags, 0, NWG * sizeof(unsigned int), stream);

  gemm1_kernel<<<dim3(64, 8), 256, 0, stream>>>(H, X_emb, visit);
  gemm2_kernel<<<dim3(64, 24), 256, 0, stream>>>(visit, W_ih, b_ih, gi);
  scan_kernel<<<NWG, 384, 0, stream>>>(gi, W_hh, b_hh, w_att, hs, logitp, flags);
  softmax_kernel<<<1, 256, 0, stream>>>(logitp, alpha, out);
  wsum_kernel<<<128, 256, 0, stream>>>(alpha, hs, out);
}